// Round 3
// baseline (143.760 us; speedup 1.0000x reference)
//
#include <hip/hip_runtime.h>

// DinoPool: block-diagonal uniform attention == per-512-row-block column mean,
// broadcast back to all 512 rows of the block.
// WORLD MODEL (derived from rounds 0-2 error statistics): x and out are
// FLOAT32 [4,4096,384] on device (reference dtype honored; the "bf16" in the
// harness label is only the comparison flavor). Earlier rounds read f32 as
// bf16 -> half-stride row bug with Var(diff)=1/512 signature. Now f32 native.

#define BB   4
#define SS   4096
#define CC   384          // H*D = 6*64
#define BLK  512
#define NBLK 8            // SS/BLK
#define NT   384          // threads per WG
#define NSUB 16           // output slices per block (kernel B)
#define RWS  (BLK / NSUB) // 32 rows per WG in kernel B

// ---------------------------------------------------------------------------
// Kernel A: partial column sums. grid = BB*NBLK*rch, block = 384.
// Thread c sums (BLK/rch) rows of channel c (wave reads 64*4B = 256B coalesced).
// ---------------------------------------------------------------------------
__global__ __launch_bounds__(NT) void colsum_f32(
    const float* __restrict__ x, float* __restrict__ ws, int rch) {
  int bid = blockIdx.x;                 // ((b*NBLK + blk)*rch + r)
  int r   = bid % rch;
  int blk = (bid / rch) % NBLK;
  int b   = bid / (rch * NBLK);
  int c   = threadIdx.x;
  int rows = BLK / rch;

  const float* p = x + (size_t)(b * SS + blk * BLK + r * rows) * CC + c;
  float acc = 0.0f;
#pragma unroll 16
  for (int i = 0; i < rows; ++i) acc += p[(size_t)i * CC];
  ws[(size_t)bid * CC + c] = acc;
}

// ---------------------------------------------------------------------------
// Kernel B: reduce rch partials -> mean row in LDS; broadcast-write 32 rows
// as float4. grid = BB*NBLK*NSUB = 512, block = 384.
// ---------------------------------------------------------------------------
__global__ __launch_bounds__(NT) void bcast_f32(
    const float* __restrict__ ws, float* __restrict__ out, int rch) {
  __shared__ __align__(16) float smean[CC];

  int bid = blockIdx.x;
  int sub = bid & (NSUB - 1);
  int blk = (bid >> 4) & (NBLK - 1);
  int b   = bid >> 7;
  int t   = threadIdx.x;

  const float* wp = ws + (size_t)((b * NBLK + blk) * rch) * CC + t;
  float s = 0.0f;
  for (int r = 0; r < rch; ++r) s += wp[(size_t)r * CC];
  smean[t] = s * (1.0f / (float)BLK);
  __syncthreads();

  const float4* sv = (const float4*)smean;  // 96 float4 chunks per row
  float4* ov = (float4*)(out + (size_t)(b * SS + blk * BLK + sub * RWS) * CC);
  const int total = RWS * (CC / 4);         // 32*96 = 3072
  for (int i = t; i < total; i += NT) ov[i] = sv[i % 96];
}

// ---------------------------------------------------------------------------
// Fallback (no workspace): one WG per (b,blk,sub) reads the whole block
// (redundant 16x, L2/L3-served) and writes its 32 rows. Used only if ws_size
// is too small for even rch=1.
// ---------------------------------------------------------------------------
__global__ __launch_bounds__(NT) void fused_f32(
    const float* __restrict__ x, float* __restrict__ out) {
  __shared__ float part[4][CC];             // 6 KB
  __shared__ __align__(16) float smean[CC];

  int bid = blockIdx.x;
  int sub = bid & (NSUB - 1);
  int blk = (bid >> 4) & (NBLK - 1);
  int b   = bid >> 7;
  int t   = threadIdx.x;
  int cq  = t % 96;                         // float4 chunk in row
  int g   = t / 96;                         // row group 0..3

  const float4* xv = (const float4*)(x + (size_t)(b * SS + blk * BLK) * CC);
  float a0 = 0.f, a1 = 0.f, a2 = 0.f, a3 = 0.f;
  for (int k = 0; k < BLK / 4; ++k) {       // rows g, g+4, ..., g+508
    float4 v = xv[(size_t)(g + 4 * k) * 96 + cq];
    a0 += v.x; a1 += v.y; a2 += v.z; a3 += v.w;
  }
  part[g][cq * 4 + 0] = a0;
  part[g][cq * 4 + 1] = a1;
  part[g][cq * 4 + 2] = a2;
  part[g][cq * 4 + 3] = a3;
  __syncthreads();

  float s = 0.f;
#pragma unroll
  for (int gg = 0; gg < 4; ++gg) s += part[gg][t];
  smean[t] = s * (1.0f / (float)BLK);
  __syncthreads();

  const float4* sv = (const float4*)smean;
  float4* ov = (float4*)(out + (size_t)(b * SS + blk * BLK + sub * RWS) * CC);
  const int total = RWS * (CC / 4);
  for (int i = t; i < total; i += NT) ov[i] = sv[i % 96];
}

extern "C" void kernel_launch(void* const* d_in, const int* in_sizes, int n_in,
                              void* d_out, int out_size, void* d_ws,
                              size_t ws_size, hipStream_t stream) {
  const float* x = (const float*)d_in[0];
  float* out = (float*)d_out;
  float* ws = (float*)d_ws;

  const size_t per_rch = (size_t)BB * NBLK * CC * sizeof(float);  // 49152 B
  int rch = 0;
  if (ws_size >= 8 * per_rch)      rch = 8;   // 393 KB: 256 WGs in kernel A
  else if (ws_size >= 4 * per_rch) rch = 4;
  else if (ws_size >= 2 * per_rch) rch = 2;
  else if (ws_size >= 1 * per_rch) rch = 1;

  if (rch > 0) {
    colsum_f32<<<BB * NBLK * rch, NT, 0, stream>>>(x, ws, rch);
    bcast_f32<<<BB * NBLK * NSUB, NT, 0, stream>>>(ws, out, rch);
  } else {
    fused_f32<<<BB * NBLK * NSUB, NT, 0, stream>>>(x, out);
  }
}